// Round 4
// baseline (210.572 us; speedup 1.0000x reference)
//
#include <hip/hip_runtime.h>

#define BN 4
#define C 256
#define H 64
#define W 64
#define CM 64
#define G 16
#define GC 16
#define KS 7
#define K2 49
#define PADD 3
#define EPSV 1e-5f

#define TS 16          // pixel tile is 16x16
#define HALO 22        // TS + KS - 1
#define HSLOT 512      // 22*22=484 padded to 512

// workspace layout (float offsets)
#define W1T_OFF 0                        // [256][64]  w1T[c][o]
#define W2G_OFF (W1T_OFF + C*CM)         // [16][64][64] w2G[g][o][k], padded, 256B-aligned rows
#define B2P_OFF (W2G_OFF + G*CM*64)      // [16][64]
#define S1_OFF  (B2P_OFF + G*64)         // [64]
#define B1_OFF  (S1_OFF + CM)            // [64]
#define S2_OFF  (B1_OFF + CM)            // [256]
#define B2C_OFF (S2_OFF + C)             // [256]
#define ZERO_OFF (B2C_OFF + C)           // [16] zeros (OOB redirect)
#define T_OFF   (ZERO_OFF + 16)          // [4][16 tiles][256 pix][64 o]

__device__ __forceinline__ void gload_lds4(const float* g, float* l) {
  __builtin_amdgcn_global_load_lds(
      (const __attribute__((address_space(1))) void*)g,
      (__attribute__((address_space(3))) void*)l, 4, 0, 0);
}

__global__ __launch_bounds__(256) void prep_kernel(
    const float* __restrict__ w1, const float* __restrict__ w2,
    const float* __restrict__ b2,
    const float* __restrict__ g1, const float* __restrict__ be1,
    const float* __restrict__ m1, const float* __restrict__ v1,
    const float* __restrict__ g2, const float* __restrict__ be2,
    const float* __restrict__ m2, const float* __restrict__ v2,
    float* __restrict__ ws) {
  int tid = blockIdx.x * 256 + threadIdx.x;
  int nthr = gridDim.x * 256;
  for (int i = tid; i < CM * C; i += nthr) {
    int o = i / C, c = i - o * C;
    ws[W1T_OFF + c * CM + o] = w1[i];
  }
  for (int i = tid; i < G * CM * 64; i += nthr) {
    int g = i >> 12;
    int o = (i >> 6) & 63;
    int k = i & 63;
    float v = 0.f;
    if (k < K2) v = w2[(g * K2 + k) * CM + o];
    ws[W2G_OFF + i] = v;
  }
  for (int i = tid; i < G * 64; i += nthr) {
    int g = i >> 6, k = i & 63;
    ws[B2P_OFF + i] = (k < K2) ? b2[g * K2 + k] : 0.f;
  }
  if (tid < CM) {
    float inv = g1[tid] * rsqrtf(v1[tid] + EPSV);
    ws[S1_OFF + tid] = inv;
    ws[B1_OFF + tid] = be1[tid] - m1[tid] * inv;
  }
  if (tid < C) {
    float inv = g2[tid] * rsqrtf(v2[tid] + EPSV);
    ws[S2_OFF + tid] = inv;
    ws[B2C_OFF + tid] = be2[tid] - m2[tid] * inv;
  }
  if (tid < 16) ws[ZERO_OFF + tid] = 0.f;
}

// t = relu(bn1(w1 @ x)), layout t[b][tile16][pix256][o64] (o fastest).
__global__ __launch_bounds__(256) void t_kernel(
    const float* __restrict__ x, const float* __restrict__ ws,
    float* __restrict__ t) {
  __shared__ float part[4][32][64];
  int p = threadIdx.x & 63;
  int q = __builtin_amdgcn_readfirstlane(threadIdx.x >> 6);
  int y = blockIdx.x, b = blockIdx.y, oh = blockIdx.z;
  const float* __restrict__ w1T = ws + W1T_OFF + oh * 32;

  float acc[32];
#pragma unroll
  for (int o = 0; o < 32; ++o) acc[o] = 0.f;
  const float* __restrict__ xrow = x + (((size_t)b * C + q * 64) * H + y) * W;
#pragma unroll 2
  for (int cc = 0; cc < 64; ++cc) {
    float xv = xrow[(size_t)cc * H * W + p];
    const float* __restrict__ wr = w1T + (q * 64 + cc) * CM;
#pragma unroll
    for (int o = 0; o < 32; ++o) acc[o] = fmaf(wr[o], xv, acc[o]);
  }
#pragma unroll
  for (int o = 0; o < 32; ++o) part[q][o][p] = acc[o];
  __syncthreads();

  int tile = (y >> 4) * 4 + (p >> 4);
  int pix = (y & 15) * 16 + (p & 15);
  const float* __restrict__ s1 = ws + S1_OFF + oh * 32;
  const float* __restrict__ b1 = ws + B1_OFF + oh * 32;
  float4 v4[2];
#pragma unroll
  for (int i = 0; i < 8; ++i) {
    int o = q * 8 + i;
    float s = part[0][o][p] + part[1][o][p] + part[2][o][p] + part[3][o][p];
    (&v4[0].x)[i] = fmaxf(fmaf(s, s1[o], b1[o]), 0.f);
  }
  float4* dst = (float4*)(t + ((size_t)(b * 16 + tile) * 256 + pix) * 64 + oh * 32 + q * 8);
  dst[0] = v4[0];
  dst[1] = v4[1];
}

// per (b, g, 16x16 tile): 4 waves share a 32KB halo; one barrier.
// phase 1: issue halo gload_lds (4 ch per wave); wgt-GEMM covers the latency.
// phase 2: barrier; 7x7 stencil from LDS, bn2+relu, store.
__global__ __launch_bounds__(256, 4) void inv_kernel(
    const float* __restrict__ x, const float* __restrict__ ws,
    const float* __restrict__ t, float* __restrict__ out) {
  __shared__ float xh[G * HSLOT];   // 32 KB
  int tid = threadIdx.x;
  int lane = tid & 63;
  int wv = __builtin_amdgcn_readfirstlane(tid >> 6);
  int tile = blockIdx.x, g = blockIdx.y, b = blockIdx.z;
  int ty = (tile >> 2) * TS, tx = (tile & 3) * TS;
  int py = tid >> 4, px = tid & 15;

  // halo chunk geometry: slot = c*64+lane; r = slot/22, cl = slot%22
  int hofs[8];
  bool hval[8];
#pragma unroll
  for (int c = 0; c < 8; ++c) {
    int slot = c * 64 + lane;
    int r = slot / 22, cl = slot - r * 22;
    int gy = ty - PADD + r, gx = tx - PADD + cl;
    bool v = (slot < 484) && ((unsigned)gy < H) && ((unsigned)gx < W);
    hval[c] = v;
    hofs[c] = gy * W + gx;
  }
  const float* __restrict__ zsrc = ws + ZERO_OFF;
  const float* __restrict__ xg = x + ((size_t)b * C + g * GC) * (H * W);
  // each wave stages 4 channels (32 gload_lds4 per wave)
#pragma unroll
  for (int j = 0; j < 4; ++j) {
    int ch = wv * 4 + j;
    const float* xc = xg + (size_t)ch * (H * W);
    float* ldst = &xh[ch * HSLOT];
#pragma unroll
    for (int c = 0; c < 8; ++c) {
      const float* s = hval[c] ? (xc + hofs[c]) : zsrc;
      gload_lds4(s, ldst + c * 64);
    }
  }

  // wgt GEMM: wgt[k] = b2p[g][k] + sum_o w2G[g][o][k] * t[o][pix]
  float wgt[K2];
  const float* __restrict__ b2g =
      (const float*)__builtin_assume_aligned(ws + B2P_OFF + g * 64, 256);
#pragma unroll
  for (int k = 0; k < K2; ++k) wgt[k] = b2g[k];

  const float4* __restrict__ tt =
      (const float4*)(t + ((size_t)(b * 16 + tile) * 256 + tid) * 64);
  const float* __restrict__ w2g =
      (const float*)__builtin_assume_aligned(ws + W2G_OFF + (size_t)g * CM * 64, 256);

  float4 cur0 = tt[0], cur1 = tt[1];
#pragma unroll 2
  for (int ck = 0; ck < 8; ++ck) {
    float4 nx0, nx1;
    if (ck < 7) {
      nx0 = tt[ck * 2 + 2];
      nx1 = tt[ck * 2 + 3];
    }
#pragma unroll
    for (int j = 0; j < 8; ++j) {
      float tv = (j < 4) ? (&cur0.x)[j] : (&cur1.x)[j - 4];
      const float* __restrict__ wr = (const float*)__builtin_assume_aligned(
          w2g + (ck * 8 + j) * 64, 256);
#pragma unroll
      for (int k = 0; k < K2; ++k) wgt[k] = fmaf(wr[k], tv, wgt[k]);
    }
    cur0 = nx0;
    cur1 = nx1;
  }

  asm volatile("s_waitcnt vmcnt(0)" ::: "memory");
  __syncthreads();

  const float* __restrict__ s2 = ws + S2_OFF + g * GC;
  const float* __restrict__ b2c = ws + B2C_OFF + g * GC;
  float* __restrict__ outg =
      out + (((size_t)b * C + g * GC) * H + ty + py) * W + tx + px;

#pragma unroll 2
  for (int ch = 0; ch < GC; ++ch) {
    const float* hb = &xh[ch * HSLOT + py * HALO + px];
    float a[4] = {0.f, 0.f, 0.f, 0.f};
#pragma unroll
    for (int di = 0; di < KS; ++di)
#pragma unroll
      for (int dj = 0; dj < KS; ++dj)
        a[di & 3] = fmaf(hb[di * HALO + dj], wgt[di * KS + dj], a[di & 3]);
    float acc = (a[0] + a[1]) + (a[2] + a[3]);
    float v = fmaxf(fmaf(acc, s2[ch], b2c[ch]), 0.f);
    outg[(size_t)ch * H * W] = v;
  }
}

extern "C" void kernel_launch(void* const* d_in, const int* in_sizes, int n_in,
                              void* d_out, int out_size, void* d_ws, size_t ws_size,
                              hipStream_t stream) {
  const float* x   = (const float*)d_in[0];
  const float* w1  = (const float*)d_in[1];
  const float* g1  = (const float*)d_in[2];
  const float* be1 = (const float*)d_in[3];
  const float* m1  = (const float*)d_in[4];
  const float* v1  = (const float*)d_in[5];
  const float* w2  = (const float*)d_in[6];
  const float* b2  = (const float*)d_in[7];
  const float* g2  = (const float*)d_in[8];
  const float* be2 = (const float*)d_in[9];
  const float* m2  = (const float*)d_in[10];
  const float* v2  = (const float*)d_in[11];
  float* outp = (float*)d_out;
  float* ws = (float*)d_ws;

  prep_kernel<<<dim3(64), dim3(256), 0, stream>>>(w1, w2, b2, g1, be1, m1, v1,
                                                  g2, be2, m2, v2, ws);
  t_kernel<<<dim3(H, BN, 2), dim3(256), 0, stream>>>(x, ws, ws + T_OFF);
  inv_kernel<<<dim3(16, G, BN), dim3(256), 0, stream>>>(x, ws, ws + T_OFF, outp);
}

// Round 5
// 151.848 us; speedup vs baseline: 1.3867x; 1.3867x over previous
//
#include <hip/hip_runtime.h>

#define BN 4
#define C 256
#define H 64
#define W 64
#define CM 64
#define G 16
#define GC 16
#define KS 7
#define K2 49
#define PADD 3
#define EPSV 1e-5f

#define TS 16          // pixel tile is 16x16
#define HALO 22        // TS + KS - 1
#define HSLOT 512      // 22*22=484 padded to 512

// workspace layout (float offsets)
#define W1T_OFF 0                        // [256][64]  w1T[c][o]
#define W2G_OFF (W1T_OFF + C*CM)         // [16][64][64] w2G[g][o][k], padded, 256B-aligned rows
#define B2P_OFF (W2G_OFF + G*CM*64)      // [16][64]
#define S1_OFF  (B2P_OFF + G*64)         // [64]
#define B1_OFF  (S1_OFF + CM)            // [64]
#define S2_OFF  (B1_OFF + CM)            // [256]
#define B2C_OFF (S2_OFF + C)             // [256]
#define ZERO_OFF (B2C_OFF + C)           // [16] zeros (OOB redirect)
#define T_OFF   (ZERO_OFF + 16)          // [4][16 tiles][256 pix][64 o]

__device__ __forceinline__ void gload_lds4(const float* g, float* l) {
  __builtin_amdgcn_global_load_lds(
      (const __attribute__((address_space(1))) void*)g,
      (__attribute__((address_space(3))) void*)l, 4, 0, 0);
}

__global__ __launch_bounds__(256) void prep_kernel(
    const float* __restrict__ w1, const float* __restrict__ w2,
    const float* __restrict__ b2,
    const float* __restrict__ g1, const float* __restrict__ be1,
    const float* __restrict__ m1, const float* __restrict__ v1,
    const float* __restrict__ g2, const float* __restrict__ be2,
    const float* __restrict__ m2, const float* __restrict__ v2,
    float* __restrict__ ws) {
  int tid = blockIdx.x * 256 + threadIdx.x;
  int nthr = gridDim.x * 256;
  for (int i = tid; i < CM * C; i += nthr) {
    int o = i / C, c = i - o * C;
    ws[W1T_OFF + c * CM + o] = w1[i];
  }
  for (int i = tid; i < G * CM * 64; i += nthr) {
    int g = i >> 12;
    int o = (i >> 6) & 63;
    int k = i & 63;
    float v = 0.f;
    if (k < K2) v = w2[(g * K2 + k) * CM + o];
    ws[W2G_OFF + i] = v;
  }
  for (int i = tid; i < G * 64; i += nthr) {
    int g = i >> 6, k = i & 63;
    ws[B2P_OFF + i] = (k < K2) ? b2[g * K2 + k] : 0.f;
  }
  if (tid < CM) {
    float inv = g1[tid] * rsqrtf(v1[tid] + EPSV);
    ws[S1_OFF + tid] = inv;
    ws[B1_OFF + tid] = be1[tid] - m1[tid] * inv;
  }
  if (tid < C) {
    float inv = g2[tid] * rsqrtf(v2[tid] + EPSV);
    ws[S2_OFF + tid] = inv;
    ws[B2C_OFF + tid] = be2[tid] - m2[tid] * inv;
  }
  if (tid < 16) ws[ZERO_OFF + tid] = 0.f;
}

// t = relu(bn1(w1 @ x)), layout t[b][tile16][pix256][o64] (o fastest).
__global__ __launch_bounds__(256) void t_kernel(
    const float* __restrict__ x, const float* __restrict__ ws,
    float* __restrict__ t) {
  __shared__ float part[4][32][64];
  int p = threadIdx.x & 63;
  int q = __builtin_amdgcn_readfirstlane(threadIdx.x >> 6);
  int y = blockIdx.x, b = blockIdx.y, oh = blockIdx.z;
  const float* __restrict__ w1T = ws + W1T_OFF + oh * 32;

  float acc[32];
#pragma unroll
  for (int o = 0; o < 32; ++o) acc[o] = 0.f;
  const float* __restrict__ xrow = x + (((size_t)b * C + q * 64) * H + y) * W;
#pragma unroll 2
  for (int cc = 0; cc < 64; ++cc) {
    float xv = xrow[(size_t)cc * H * W + p];
    const float* __restrict__ wr = w1T + (q * 64 + cc) * CM;
#pragma unroll
    for (int o = 0; o < 32; ++o) acc[o] = fmaf(wr[o], xv, acc[o]);
  }
#pragma unroll
  for (int o = 0; o < 32; ++o) part[q][o][p] = acc[o];
  __syncthreads();

  int tile = (y >> 4) * 4 + (p >> 4);
  int pix = (y & 15) * 16 + (p & 15);
  const float* __restrict__ s1 = ws + S1_OFF + oh * 32;
  const float* __restrict__ b1 = ws + B1_OFF + oh * 32;
  float4 v4[2];
#pragma unroll
  for (int i = 0; i < 8; ++i) {
    int o = q * 8 + i;
    float s = part[0][o][p] + part[1][o][p] + part[2][o][p] + part[3][o][p];
    (&v4[0].x)[i] = fmaxf(fmaf(s, s1[o], b1[o]), 0.f);
  }
  float4* dst = (float4*)(t + ((size_t)(b * 16 + tile) * 256 + pix) * 64 + oh * 32 + q * 8);
  dst[0] = v4[0];
  dst[1] = v4[1];
}

// per (b, g, 16x16 tile): 4 waves share a 32KB halo; one barrier.
// phase 1: issue halo gload_lds (4 ch per wave); wgt-GEMM covers the latency.
// phase 2: barrier; 7x7 stencil from LDS, bn2+relu, store.
__global__ __launch_bounds__(256, 2) void inv_kernel(
    const float* __restrict__ x, const float* __restrict__ ws,
    const float* __restrict__ t, float* __restrict__ out) {
  __shared__ float xh[G * HSLOT];   // 32 KB
  int tid = threadIdx.x;
  int lane = tid & 63;
  int wv = __builtin_amdgcn_readfirstlane(tid >> 6);
  int tile = blockIdx.x, g = blockIdx.y, b = blockIdx.z;
  int ty = (tile >> 2) * TS, tx = (tile & 3) * TS;
  int py = tid >> 4, px = tid & 15;

  // halo chunk geometry: slot = c*64+lane; r = slot/22, cl = slot%22
  int hofs[8];
  bool hval[8];
#pragma unroll
  for (int c = 0; c < 8; ++c) {
    int slot = c * 64 + lane;
    int r = slot / 22, cl = slot - r * 22;
    int gy = ty - PADD + r, gx = tx - PADD + cl;
    bool v = (slot < 484) && ((unsigned)gy < H) && ((unsigned)gx < W);
    hval[c] = v;
    hofs[c] = gy * W + gx;
  }
  const float* __restrict__ zsrc = ws + ZERO_OFF;
  const float* __restrict__ xg = x + ((size_t)b * C + g * GC) * (H * W);
  // each wave stages 4 channels (32 gload_lds4 per wave)
#pragma unroll
  for (int j = 0; j < 4; ++j) {
    int ch = wv * 4 + j;
    const float* xc = xg + (size_t)ch * (H * W);
    float* ldst = &xh[ch * HSLOT];
#pragma unroll
    for (int c = 0; c < 8; ++c) {
      const float* s = hval[c] ? (xc + hofs[c]) : zsrc;
      gload_lds4(s, ldst + c * 64);
    }
  }

  // wgt GEMM: wgt[k] = b2p[g][k] + sum_o w2G[g][o][k] * t[o][pix]
  float wgt[K2];
  const float* __restrict__ b2g =
      (const float*)__builtin_assume_aligned(ws + B2P_OFF + g * 64, 256);
#pragma unroll
  for (int k = 0; k < K2; ++k) wgt[k] = b2g[k];

  const float4* __restrict__ tt =
      (const float4*)(t + ((size_t)(b * 16 + tile) * 256 + tid) * 64);
  const float* __restrict__ w2g =
      (const float*)__builtin_assume_aligned(ws + W2G_OFF + (size_t)g * CM * 64, 256);

  float4 cur0 = tt[0], cur1 = tt[1];
#pragma unroll 2
  for (int ck = 0; ck < 8; ++ck) {
    float4 nx0, nx1;
    if (ck < 7) {
      nx0 = tt[ck * 2 + 2];
      nx1 = tt[ck * 2 + 3];
    }
#pragma unroll
    for (int j = 0; j < 8; ++j) {
      float tv = (j < 4) ? (&cur0.x)[j] : (&cur1.x)[j - 4];
      const float* __restrict__ wr = (const float*)__builtin_assume_aligned(
          w2g + (ck * 8 + j) * 64, 256);
#pragma unroll
      for (int k = 0; k < K2; ++k) wgt[k] = fmaf(wr[k], tv, wgt[k]);
    }
    cur0 = nx0;
    cur1 = nx1;
  }

  asm volatile("s_waitcnt vmcnt(0)" ::: "memory");
  __syncthreads();

  const float* __restrict__ s2 = ws + S2_OFF + g * GC;
  const float* __restrict__ b2c = ws + B2C_OFF + g * GC;
  float* __restrict__ outg =
      out + (((size_t)b * C + g * GC) * H + ty + py) * W + tx + px;

#pragma unroll 2
  for (int ch = 0; ch < GC; ++ch) {
    const float* hb = &xh[ch * HSLOT + py * HALO + px];
    float a[4] = {0.f, 0.f, 0.f, 0.f};
#pragma unroll
    for (int di = 0; di < KS; ++di)
#pragma unroll
      for (int dj = 0; dj < KS; ++dj)
        a[di & 3] = fmaf(hb[di * HALO + dj], wgt[di * KS + dj], a[di & 3]);
    float acc = (a[0] + a[1]) + (a[2] + a[3]);
    float v = fmaxf(fmaf(acc, s2[ch], b2c[ch]), 0.f);
    outg[(size_t)ch * H * W] = v;
  }
}

extern "C" void kernel_launch(void* const* d_in, const int* in_sizes, int n_in,
                              void* d_out, int out_size, void* d_ws, size_t ws_size,
                              hipStream_t stream) {
  const float* x   = (const float*)d_in[0];
  const float* w1  = (const float*)d_in[1];
  const float* g1  = (const float*)d_in[2];
  const float* be1 = (const float*)d_in[3];
  const float* m1  = (const float*)d_in[4];
  const float* v1  = (const float*)d_in[5];
  const float* w2  = (const float*)d_in[6];
  const float* b2  = (const float*)d_in[7];
  const float* g2  = (const float*)d_in[8];
  const float* be2 = (const float*)d_in[9];
  const float* m2  = (const float*)d_in[10];
  const float* v2  = (const float*)d_in[11];
  float* outp = (float*)d_out;
  float* ws = (float*)d_ws;

  prep_kernel<<<dim3(64), dim3(256), 0, stream>>>(w1, w2, b2, g1, be1, m1, v1,
                                                  g2, be2, m2, v2, ws);
  t_kernel<<<dim3(H, BN, 2), dim3(256), 0, stream>>>(x, ws, ws + T_OFF);
  inv_kernel<<<dim3(16, G, BN), dim3(256), 0, stream>>>(x, ws, ws + T_OFF, outp);
}

// Round 6
// 100.663 us; speedup vs baseline: 2.0919x; 1.5085x over previous
//
#include <hip/hip_runtime.h>

#define BN 4
#define C 256
#define H 64
#define W 64
#define CM 64
#define G 16
#define GC 16
#define KS 7
#define K2 49
#define PADD 3
#define EPSV 1e-5f

#define TS 16          // pixel tile is 16x16
#define HALO 22        // TS + KS - 1
#define HSLOT 512      // 22*22=484 padded to 512

// workspace layout (float offsets)
#define W1T_OFF 0                        // [256][64]  w1T[c][o]
#define W2G_OFF (W1T_OFF + C*CM)         // [16][64][64] w2G[g][o][k], k padded 49->64
#define B2P_OFF (W2G_OFF + G*CM*64)      // [16][64]
#define S1_OFF  (B2P_OFF + G*64)         // [64]
#define B1_OFF  (S1_OFF + CM)            // [64]
#define S2_OFF  (B1_OFF + CM)            // [256]
#define B2C_OFF (S2_OFF + C)             // [256]
#define ZERO_OFF (B2C_OFF + C)           // [16] zeros (OOB redirect)
#define T_OFF   (ZERO_OFF + 16)          // [4][16 tiles][16 quads][256 pix][4]

__device__ __forceinline__ void gload_lds4(const float* g, float* l) {
  __builtin_amdgcn_global_load_lds(
      (const __attribute__((address_space(1))) void*)g,
      (__attribute__((address_space(3))) void*)l, 4, 0, 0);
}

__global__ __launch_bounds__(256) void prep_kernel(
    const float* __restrict__ w1, const float* __restrict__ w2,
    const float* __restrict__ b2,
    const float* __restrict__ g1, const float* __restrict__ be1,
    const float* __restrict__ m1, const float* __restrict__ v1,
    const float* __restrict__ g2, const float* __restrict__ be2,
    const float* __restrict__ m2, const float* __restrict__ v2,
    float* __restrict__ ws) {
  int tid = blockIdx.x * 256 + threadIdx.x;
  int nthr = gridDim.x * 256;
  for (int i = tid; i < CM * C; i += nthr) {
    int o = i / C, c = i - o * C;
    ws[W1T_OFF + c * CM + o] = w1[i];
  }
  // w2 [784][64] -> w2G[g][o][64] (k<49 real, else 0)
  for (int i = tid; i < G * CM * 64; i += nthr) {
    int g = i >> 12;
    int o = (i >> 6) & 63;
    int k = i & 63;
    float v = 0.f;
    if (k < K2) v = w2[(g * K2 + k) * CM + o];
    ws[W2G_OFF + i] = v;
  }
  for (int i = tid; i < G * 64; i += nthr) {
    int g = i >> 6, k = i & 63;
    ws[B2P_OFF + i] = (k < K2) ? b2[g * K2 + k] : 0.f;
  }
  if (tid < CM) {
    float inv = g1[tid] * rsqrtf(v1[tid] + EPSV);
    ws[S1_OFF + tid] = inv;
    ws[B1_OFF + tid] = be1[tid] - m1[tid] * inv;
  }
  if (tid < C) {
    float inv = g2[tid] * rsqrtf(v2[tid] + EPSV);
    ws[S2_OFF + tid] = inv;
    ws[B2C_OFF + tid] = be2[tid] - m2[tid] * inv;
  }
  if (tid < 16) ws[ZERO_OFF + tid] = 0.f;
}

// t = relu(bn1(w1 @ x)), quad-interleaved: T4[((b*16+tile)*16 + o/4)*256 + pix]
// holds floats (o%4 = 0..3). Both store (here) and load (inv) are lane-contiguous.
__global__ __launch_bounds__(256) void t_kernel(
    const float* __restrict__ x, const float* __restrict__ ws,
    float* __restrict__ t) {
  __shared__ float part[4][32][64];
  int p = threadIdx.x & 63;
  int q = __builtin_amdgcn_readfirstlane(threadIdx.x >> 6);
  int y = blockIdx.x, b = blockIdx.y, oh = blockIdx.z;
  const float* __restrict__ w1T = ws + W1T_OFF + oh * 32;

  float acc[32];
#pragma unroll
  for (int o = 0; o < 32; ++o) acc[o] = 0.f;
  const float* __restrict__ xrow = x + (((size_t)b * C + q * 64) * H + y) * W;
#pragma unroll 2
  for (int cc = 0; cc < 64; ++cc) {
    float xv = xrow[(size_t)cc * H * W + p];
    const float* __restrict__ wr = w1T + (q * 64 + cc) * CM;
#pragma unroll
    for (int o = 0; o < 32; ++o) acc[o] = fmaf(wr[o], xv, acc[o]);
  }
#pragma unroll
  for (int o = 0; o < 32; ++o) part[q][o][p] = acc[o];
  __syncthreads();

  int tile = (y >> 4) * 4 + (p >> 4);
  int pix = (y & 15) * 16 + (p & 15);
  const float* __restrict__ s1 = ws + S1_OFF + oh * 32;
  const float* __restrict__ b1 = ws + B1_OFF + oh * 32;
  float4 v4[2];
#pragma unroll
  for (int i = 0; i < 8; ++i) {
    int o = q * 8 + i;
    float s = part[0][o][p] + part[1][o][p] + part[2][o][p] + part[3][o][p];
    (&v4[0].x)[i] = fmaxf(fmaf(s, s1[o], b1[o]), 0.f);
  }
  int Q0 = oh * 8 + q * 2;   // o-quad of v4[0]; v4[1] is Q0+1
  float4* t4 = (float4*)t;
  size_t base = ((size_t)(b * 16 + tile) * 16 + Q0) * 256 + pix;
  t4[base] = v4[0];
  t4[base + 256] = v4[1];
}

// per (b, g, 16x16 tile): 4 waves, 48KB LDS (32KB halo + 16KB weights).
// weights read from LDS via broadcast ds_read (no scalar path, no SGPR pressure).
__global__ __launch_bounds__(256, 2) void inv_kernel(
    const float* __restrict__ x, const float* __restrict__ ws,
    const float* __restrict__ t, float* __restrict__ out) {
  __shared__ float xh[G * HSLOT];   // 32 KB halo
  __shared__ float w2s[CM * 64];    // 16 KB group weight slab [o][k]
  int tid = threadIdx.x;
  int lane = tid & 63;
  int wv = __builtin_amdgcn_readfirstlane(tid >> 6);
  int tile = blockIdx.x, g = blockIdx.y, b = blockIdx.z;
  int ty = (tile >> 2) * TS, tx = (tile & 3) * TS;
  int py = tid >> 4, px = tid & 15;

  const float4* __restrict__ t4 =
      (const float4*)t + ((size_t)(b * 16 + tile) * 16) * 256 + tid;

  // --- issue phase ---------------------------------------------------------
  // (1) t chunk 1: quads 0..7 (8 coalesced float4 loads)
  float4 tr0[8];
#pragma unroll
  for (int i = 0; i < 8; ++i) tr0[i] = t4[i * 256];

  // (2) weight slab -> LDS (16 insts/wave, lane-contiguous src, linear dst)
  {
    const float* src = ws + W2G_OFF + (size_t)g * CM * 64 + wv * 1024 + lane;
    float* dst = &w2s[wv * 1024];
#pragma unroll
    for (int i = 0; i < 16; ++i) gload_lds4(src + i * 64, dst + i * 64);
  }

  // (3) halo: 4 channels per wave, 8 insts each (32 insts/wave)
  {
    int hofs[8];
    bool hval[8];
#pragma unroll
    for (int c = 0; c < 8; ++c) {
      int slot = c * 64 + lane;
      int r = slot / 22, cl = slot - r * 22;
      int gy = ty - PADD + r, gx = tx - PADD + cl;
      bool v = (slot < 484) && ((unsigned)gy < H) && ((unsigned)gx < W);
      hval[c] = v;
      hofs[c] = gy * W + gx;
    }
    const float* __restrict__ zsrc = ws + ZERO_OFF;
    const float* __restrict__ xg = x + ((size_t)b * C + g * GC) * (H * W);
#pragma unroll
    for (int j = 0; j < 4; ++j) {
      int ch = wv * 4 + j;
      const float* xc = xg + (size_t)ch * (H * W);
      float* ldst = &xh[ch * HSLOT];
#pragma unroll
      for (int c = 0; c < 8; ++c) {
        const float* s = hval[c] ? (xc + hofs[c]) : zsrc;
        gload_lds4(s, ldst + c * 64);
      }
    }
  }

  // weights (and t chunk1) complete; halo (32) may stay outstanding
  asm volatile("s_waitcnt vmcnt(32)" ::: "memory");
  __syncthreads();

  // (4) t chunk 2: quads 8..15 (completes while GEMM chews chunk 1)
  float4 tr1[8];
#pragma unroll
  for (int i = 0; i < 8; ++i) tr1[i] = t4[(8 + i) * 256];

  // --- wgt GEMM: wgt[k] = b2p[g][k] + sum_o w2s[o][k] * t[o][pix] ----------
  float wgt[K2];
  {
    const float* __restrict__ b2g = ws + B2P_OFF + g * 64;
#pragma unroll
    for (int k = 0; k < K2; ++k) wgt[k] = b2g[k];
  }
#pragma unroll
  for (int Q = 0; Q < 16; ++Q) {
#pragma unroll
    for (int j = 0; j < 4; ++j) {
      int o = Q * 4 + j;
      float tv = (Q < 8) ? (&tr0[Q].x)[j] : (&tr1[Q - 8].x)[j];
      const float* __restrict__ wr = &w2s[o * 64];   // broadcast ds_read
#pragma unroll
      for (int k = 0; k < K2; ++k) wgt[k] = fmaf(wr[k], tv, wgt[k]);
    }
  }

  asm volatile("s_waitcnt vmcnt(0)" ::: "memory");
  __syncthreads();

  // --- 7x7 stencil + bn2 + relu -------------------------------------------
  const float* __restrict__ s2 = ws + S2_OFF + g * GC;
  const float* __restrict__ b2c = ws + B2C_OFF + g * GC;
  float* __restrict__ outg =
      out + (((size_t)b * C + g * GC) * H + ty + py) * W + tx + px;

#pragma unroll 2
  for (int ch = 0; ch < GC; ++ch) {
    const float* hb = &xh[ch * HSLOT + py * HALO + px];
    float a[4] = {0.f, 0.f, 0.f, 0.f};
#pragma unroll
    for (int di = 0; di < KS; ++di)
#pragma unroll
      for (int dj = 0; dj < KS; ++dj)
        a[di & 3] = fmaf(hb[di * HALO + dj], wgt[di * KS + dj], a[di & 3]);
    float acc = (a[0] + a[1]) + (a[2] + a[3]);
    float v = fmaxf(fmaf(acc, s2[ch], b2c[ch]), 0.f);
    outg[(size_t)ch * H * W] = v;
  }
}

extern "C" void kernel_launch(void* const* d_in, const int* in_sizes, int n_in,
                              void* d_out, int out_size, void* d_ws, size_t ws_size,
                              hipStream_t stream) {
  const float* x   = (const float*)d_in[0];
  const float* w1  = (const float*)d_in[1];
  const float* g1  = (const float*)d_in[2];
  const float* be1 = (const float*)d_in[3];
  const float* m1  = (const float*)d_in[4];
  const float* v1  = (const float*)d_in[5];
  const float* w2  = (const float*)d_in[6];
  const float* b2  = (const float*)d_in[7];
  const float* g2  = (const float*)d_in[8];
  const float* be2 = (const float*)d_in[9];
  const float* m2  = (const float*)d_in[10];
  const float* v2  = (const float*)d_in[11];
  float* outp = (float*)d_out;
  float* ws = (float*)d_ws;

  prep_kernel<<<dim3(64), dim3(256), 0, stream>>>(w1, w2, b2, g1, be1, m1, v1,
                                                  g2, be2, m2, v2, ws);
  t_kernel<<<dim3(H, BN, 2), dim3(256), 0, stream>>>(x, ws, ws + T_OFF);
  inv_kernel<<<dim3(16, G, BN), dim3(256), 0, stream>>>(x, ws, ws + T_OFF, outp);
}

// Round 7
// 57.882 us; speedup vs baseline: 3.6379x; 1.7391x over previous
//
#include <hip/hip_runtime.h>

#define BN 4
#define C 256
#define H 64
#define W 64
#define CM 64
#define G 16
#define GC 16
#define KS 7
#define K2 49
#define PADD 3
#define EPSV 1e-5f

#define TS 16
#define HALO_R 22
#define HROWF 32                 // padded halo row (floats)
#define HSLOTF (HALO_R * HROWF)  // 704 floats per channel slab

// workspace layout (float offsets)
#define W1T_OFF 0                       // [256][64] w1T[c][o]
#define B2P_OFF (W1T_OFF + C*CM)        // [16][64] padded bias
#define S1_OFF  (B2P_OFF + G*64)
#define B1_OFF  (S1_OFF + CM)
#define S2_OFF  (B1_OFF + CM)
#define B2C_OFF (S2_OFF + C)
#define ZERO_OFF (B2C_OFF + C)          // [16] zeros
#define ABF_OFF (ZERO_OFF + 16)         // ushort region: A-frags 16g*4mt*2ks*64lane*8 = 65536 u16
#define TBF_OFF (ABF_OFF + 32768)       // ushort region: t bf16 [4][16tile][256pix][64o] = 1048576 u16

typedef __attribute__((ext_vector_type(8))) short bf16x8;
typedef __attribute__((ext_vector_type(4))) float f32x4;

__device__ __forceinline__ uint f2bf_rne(float f) {
  uint u = __float_as_uint(f);
  return (u + 0x7fffu + ((u >> 16) & 1u)) >> 16;
}

__device__ __forceinline__ void gload_lds4(const float* g, float* l) {
  __builtin_amdgcn_global_load_lds(
      (const __attribute__((address_space(1))) void*)g,
      (__attribute__((address_space(3))) void*)l, 4, 0, 0);
}

__global__ __launch_bounds__(256) void prep_kernel(
    const float* __restrict__ w1, const float* __restrict__ w2,
    const float* __restrict__ b2,
    const float* __restrict__ g1, const float* __restrict__ be1,
    const float* __restrict__ m1, const float* __restrict__ v1,
    const float* __restrict__ g2, const float* __restrict__ be2,
    const float* __restrict__ m2, const float* __restrict__ v2,
    float* __restrict__ ws) {
  int tid = blockIdx.x * 256 + threadIdx.x;
  int nthr = gridDim.x * 256;
  // transpose w1 [64][256] -> w1T [256][64]
  for (int i = tid; i < CM * C; i += nthr) {
    int o = i / C, c = i - o * C;
    ws[W1T_OFF + c * CM + o] = w1[i];
  }
  // A fragments (bf16) for mfma_f32_16x16x32_bf16:
  // lane l holds A[row = mt*16 + (l&15)][k = ks*32 + (l>>4)*8 + j], j=0..7
  {
    ushort* abf = (ushort*)(ws + ABF_OFF);
    for (int i = tid; i < G * 4 * 2 * 64 * 8; i += nthr) {
      int j = i & 7, lane = (i >> 3) & 63, ks = (i >> 9) & 1;
      int mt = (i >> 10) & 3, g = (i >> 12) & 15;
      int m = mt * 16 + (lane & 15);
      int o = ks * 32 + ((lane >> 4) << 3) + j;
      float v = (m < K2) ? w2[(g * K2 + m) * CM + o] : 0.f;
      abf[i] = (ushort)f2bf_rne(v);
    }
  }
  for (int i = tid; i < G * 64; i += nthr) {
    int g = i >> 6, k = i & 63;
    ws[B2P_OFF + i] = (k < K2) ? b2[g * K2 + k] : 0.f;
  }
  if (tid < CM) {
    float inv = g1[tid] * rsqrtf(v1[tid] + EPSV);
    ws[S1_OFF + tid] = inv;
    ws[B1_OFF + tid] = be1[tid] - m1[tid] * inv;
  }
  if (tid < C) {
    float inv = g2[tid] * rsqrtf(v2[tid] + EPSV);
    ws[S2_OFF + tid] = inv;
    ws[B2C_OFF + tid] = be2[tid] - m2[tid] * inv;
  }
  if (tid < 16) ws[ZERO_OFF + tid] = 0.f;
}

// t = relu(bn1(w1 @ x)) stored as bf16, layout [b][tile16][pix256][o64].
__global__ __launch_bounds__(256) void t_kernel(
    const float* __restrict__ x, float* __restrict__ ws) {
  __shared__ float part[4][32][64];
  int p = threadIdx.x & 63;
  int q = __builtin_amdgcn_readfirstlane(threadIdx.x >> 6);
  int y = blockIdx.x, b = blockIdx.y, oh = blockIdx.z;
  const float* __restrict__ w1T = ws + W1T_OFF + oh * 32;

  float acc[32];
#pragma unroll
  for (int o = 0; o < 32; ++o) acc[o] = 0.f;
  const float* __restrict__ xrow = x + (((size_t)b * C + q * 64) * H + y) * W;
#pragma unroll 2
  for (int cc = 0; cc < 64; ++cc) {
    float xv = xrow[(size_t)cc * H * W + p];
    const float* __restrict__ wr = w1T + (q * 64 + cc) * CM;
#pragma unroll
    for (int o = 0; o < 32; ++o) acc[o] = fmaf(wr[o], xv, acc[o]);
  }
#pragma unroll
  for (int o = 0; o < 32; ++o) part[q][o][p] = acc[o];
  __syncthreads();

  int tile = (y >> 4) * 4 + (p >> 4);
  int pix = (y & 15) * 16 + (p & 15);
  const float* __restrict__ s1 = ws + S1_OFF + oh * 32;
  const float* __restrict__ b1 = ws + B1_OFF + oh * 32;
  float fv[8];
#pragma unroll
  for (int i = 0; i < 8; ++i) {
    int o = q * 8 + i;
    float s = part[0][o][p] + part[1][o][p] + part[2][o][p] + part[3][o][p];
    fv[i] = fmaxf(fmaf(s, s1[o], b1[o]), 0.f);
  }
  uint4 pk;
  pk.x = f2bf_rne(fv[0]) | (f2bf_rne(fv[1]) << 16);
  pk.y = f2bf_rne(fv[2]) | (f2bf_rne(fv[3]) << 16);
  pk.z = f2bf_rne(fv[4]) | (f2bf_rne(fv[5]) << 16);
  pk.w = f2bf_rne(fv[6]) | (f2bf_rne(fv[7]) << 16);
  ushort* tbf = (ushort*)(ws + TBF_OFF);
  size_t idx = (((size_t)(b * 16 + tile) * 256 + pix) * 64) + oh * 32 + q * 8;
  *(uint4*)(tbf + idx) = pk;
}

// per (b, g, 16x16 tile): MFMA wgt-GEMM -> LDS (bf16 pairs, swizzled),
// halo staged via global_load_lds (chunk-swizzled rows), one barrier,
// then 4px/lane stencil with ds_read_b128 rows.
__global__ __launch_bounds__(256, 1) void inv_kernel(
    const float* __restrict__ x, const float* __restrict__ ws,
    float* __restrict__ out) {
  __shared__ uint wgt_u[256 * 32];     // 32 KB: per pixel 32 u32 = 64 bf16 k
  __shared__ float xh[G * HSLOTF];     // 44 KB halo

  int tid = threadIdx.x;
  int lane = tid & 63;
  int wv = __builtin_amdgcn_readfirstlane(tid >> 6);
  int c16 = lane & 15, q = lane >> 4;
  int tile = blockIdx.x, g = blockIdx.y, b = blockIdx.z;
  int ty = (tile >> 2) * TS, tx = (tile & 3) * TS;

  const ushort* abf = (const ushort*)(ws + ABF_OFF);
  const ushort* tbf = (const ushort*)(ws + TBF_OFF);

  // ---- issue A/B fragment + bias loads FIRST (their waits then leave the
  // halo loads outstanding), then halo gload_lds ------------------------
  bf16x8 afr[4][2], bfr[4][2];
  f32x4 bias[4];
#pragma unroll
  for (int mt = 0; mt < 4; ++mt) {
#pragma unroll
    for (int ks = 0; ks < 2; ++ks)
      afr[mt][ks] = *(const bf16x8*)(abf + (((g * 8 + mt * 2 + ks) * 64 + lane) * 8));
    bias[mt] = *(const f32x4*)(ws + B2P_OFF + g * 64 + mt * 16 + q * 4);
  }
#pragma unroll
  for (int nt = 0; nt < 4; ++nt) {
    int pix = wv * 64 + nt * 16 + c16;
#pragma unroll
    for (int ks = 0; ks < 2; ++ks)
      bfr[nt][ks] = *(const bf16x8*)(
          tbf + (((size_t)(b * 16 + tile) * 256 + pix) * 64 + ks * 32 + q * 8));
  }

  {
    const float* zsrc = ws + ZERO_OFF;
    const float* xg = x + ((size_t)b * C + g * GC) * (H * W);
#pragma unroll
    for (int j = 0; j < 4; ++j) {
      int ch = wv * 4 + j;
      const float* xc = xg + (size_t)ch * (H * W);
      float* ldst = &xh[ch * HSLOTF];
#pragma unroll
      for (int t2 = 0; t2 < 11; ++t2) {
        int f = t2 * 64 + lane;
        int row = f >> 5;
        int cp = (f >> 2) & 7, sub = f & 3;
        int col = (((cp ^ (row & 7)) << 2)) + sub;   // chunk-swizzled column
        int gy = ty + row - PADD, gx = tx + col - PADD;
        bool v = (col < HALO_R) && ((unsigned)gy < H) && ((unsigned)gx < W);
        const float* s = v ? (xc + gy * W + gx) : zsrc;
        gload_lds4(s, ldst + t2 * 64);
      }
    }
  }

  // ---- MFMA GEMM: wgt[m=49pad64][pix] = A @ t + bias ----------------------
  f32x4 acc[4][4];
#pragma unroll
  for (int nt = 0; nt < 4; ++nt)
#pragma unroll
    for (int mt = 0; mt < 4; ++mt) acc[nt][mt] = bias[mt];
#pragma unroll
  for (int ks = 0; ks < 2; ++ks)
#pragma unroll
    for (int nt = 0; nt < 4; ++nt)
#pragma unroll
      for (int mt = 0; mt < 4; ++mt)
        acc[nt][mt] = __builtin_amdgcn_mfma_f32_16x16x32_bf16(
            afr[mt][ks], bfr[nt][ks], acc[nt][mt], 0, 0, 0);

  // ---- pack D (row=k= mt*16+q*4+r, col=pix) to bf16-pairs, rotated row ----
#pragma unroll
  for (int nt = 0; nt < 4; ++nt) {
    int pix = wv * 64 + nt * 16 + c16;
    int swz = ((pix >> 4) << 2) + ((pix >> 2) & 3);
    uint* wrow = &wgt_u[pix * 32];
#pragma unroll
    for (int mt = 0; mt < 4; ++mt) {
      uint lo = f2bf_rne(acc[nt][mt].x) | (f2bf_rne(acc[nt][mt].y) << 16);
      uint hi = f2bf_rne(acc[nt][mt].z) | (f2bf_rne(acc[nt][mt].w) << 16);
      int i0 = mt * 8 + q * 2;
      wrow[(i0 + swz) & 31] = lo;
      wrow[(i0 + 1 + swz) & 31] = hi;
    }
  }

  __syncthreads();   // drains vmcnt (halo) + lgkm (wgt writes)

  // ---- stencil: lane = (py, 4 px), 4 channels per wave --------------------
  int py = lane >> 2;
  int px0 = (lane & 3) << 2;
  int P = px0 >> 2;

  uint wp[4][25];
#pragma unroll
  for (int i = 0; i < 4; ++i) {
    int p = py * 16 + px0 + i;
    int swz = ((p >> 4) << 2) + ((p >> 2) & 3);
    const uint* wrow = &wgt_u[p * 32];
#pragma unroll
    for (int t = 0; t < 25; ++t) wp[i][t] = wrow[(t + swz) & 31];
  }

  const float* s2 = ws + S2_OFF + g * GC;
  const float* b2c = ws + B2C_OFF + g * GC;

#pragma unroll
  for (int jc = 0; jc < 4; ++jc) {
    int ch = wv * 4 + jc;
    const float* hch = &xh[ch * HSLOTF];
    float a0 = 0.f, a1 = 0.f, a2 = 0.f, a3 = 0.f;
#pragma unroll
    for (int di = 0; di < KS; ++di) {
      int row = py + di;
      int r7 = row & 7;
      f32x4 h0 = *(const f32x4*)&hch[row * HROWF + (((P + 0) ^ r7) << 2)];
      f32x4 h1 = *(const f32x4*)&hch[row * HROWF + (((P + 1) ^ r7) << 2)];
      f32x4 h2 = *(const f32x4*)&hch[row * HROWF + (((P + 2) ^ r7) << 2)];
      float rw[12] = {h0.x, h0.y, h0.z, h0.w, h1.x, h1.y, h1.z, h1.w,
                      h2.x, h2.y, h2.z, h2.w};
#pragma unroll
      for (int dj = 0; dj < KS; ++dj) {
        int k = di * KS + dj;
        uint m0 = wp[0][k >> 1], m1 = wp[1][k >> 1];
        uint m2v = wp[2][k >> 1], m3 = wp[3][k >> 1];
        float w0, w1, w2f, w3;
        if (k & 1) {
          w0 = __uint_as_float(m0 & 0xffff0000u);
          w1 = __uint_as_float(m1 & 0xffff0000u);
          w2f = __uint_as_float(m2v & 0xffff0000u);
          w3 = __uint_as_float(m3 & 0xffff0000u);
        } else {
          w0 = __uint_as_float(m0 << 16);
          w1 = __uint_as_float(m1 << 16);
          w2f = __uint_as_float(m2v << 16);
          w3 = __uint_as_float(m3 << 16);
        }
        a0 = fmaf(rw[0 + dj], w0, a0);
        a1 = fmaf(rw[1 + dj], w1, a1);
        a2 = fmaf(rw[2 + dj], w2f, a2);
        a3 = fmaf(rw[3 + dj], w3, a3);
      }
    }
    float sc = s2[ch], bc = b2c[ch];
    float4 o4;
    o4.x = fmaxf(fmaf(a0, sc, bc), 0.f);
    o4.y = fmaxf(fmaf(a1, sc, bc), 0.f);
    o4.z = fmaxf(fmaf(a2, sc, bc), 0.f);
    o4.w = fmaxf(fmaf(a3, sc, bc), 0.f);
    *(float4*)(out + (((size_t)b * C + g * GC + ch) * H + ty + py) * W + tx + px0) = o4;
  }
}

extern "C" void kernel_launch(void* const* d_in, const int* in_sizes, int n_in,
                              void* d_out, int out_size, void* d_ws, size_t ws_size,
                              hipStream_t stream) {
  const float* x   = (const float*)d_in[0];
  const float* w1  = (const float*)d_in[1];
  const float* g1  = (const float*)d_in[2];
  const float* be1 = (const float*)d_in[3];
  const float* m1  = (const float*)d_in[4];
  const float* v1  = (const float*)d_in[5];
  const float* w2  = (const float*)d_in[6];
  const float* b2  = (const float*)d_in[7];
  const float* g2  = (const float*)d_in[8];
  const float* be2 = (const float*)d_in[9];
  const float* m2  = (const float*)d_in[10];
  const float* v2  = (const float*)d_in[11];
  float* outp = (float*)d_out;
  float* ws = (float*)d_ws;

  prep_kernel<<<dim3(64), dim3(256), 0, stream>>>(w1, w2, b2, g1, be1, m1, v1,
                                                  g2, be2, m2, v2, ws);
  t_kernel<<<dim3(H, BN, 2), dim3(256), 0, stream>>>(x, ws);
  inv_kernel<<<dim3(16, G, BN), dim3(256), 0, stream>>>(x, ws, outp);
}

// Round 8
// 47.610 us; speedup vs baseline: 4.4228x; 1.2157x over previous
//
#include <hip/hip_runtime.h>

#define BN 4
#define C 256
#define H 64
#define W 64
#define CM 64
#define G 16
#define GC 16
#define KS 7
#define K2 49
#define PADD 3
#define EPSV 1e-5f

#define TS 16
#define HALO_R 22
#define HROWF 32     // padded halo row (floats)
#define HSLOTP 712   // per-channel slab stride (22*32=704, +8 pad for bank spread)

// workspace layout (float offsets)
#define W1T_OFF 0                       // [256][64] w1T[c][o]
#define B2P_OFF (W1T_OFF + C*CM)        // [16][64] padded bias
#define S1_OFF  (B2P_OFF + G*64)
#define B1_OFF  (S1_OFF + CM)
#define S2_OFF  (B1_OFF + CM)
#define B2C_OFF (S2_OFF + C)
#define ZERO_OFF (B2C_OFF + C)          // [16] zeros
#define ABF_OFF (ZERO_OFF + 16)         // ushort: A-frags 16g*4mt*2ks*64lane*8
#define TBF_OFF (ABF_OFF + 32768)       // ushort: t bf16 [4][16tile][256pix][64o]

typedef __attribute__((ext_vector_type(8))) short bf16x8;
typedef __attribute__((ext_vector_type(4))) float f32x4;

__device__ __forceinline__ uint f2bf_rne(float f) {
  uint u = __float_as_uint(f);
  return (u + 0x7fffu + ((u >> 16) & 1u)) >> 16;
}

__device__ __forceinline__ void gload_lds4(const float* g, float* l) {
  __builtin_amdgcn_global_load_lds(
      (const __attribute__((address_space(1))) void*)g,
      (__attribute__((address_space(3))) void*)l, 4, 0, 0);
}

#define WAITBAR(N) do {                                            \
    asm volatile("s_waitcnt vmcnt(" #N ") lgkmcnt(0)" ::: "memory"); \
    __builtin_amdgcn_s_barrier();                                  \
    __builtin_amdgcn_sched_barrier(0);                             \
  } while (0)

#define BARRIER_ONLY() do {                                        \
    asm volatile("s_waitcnt lgkmcnt(0)" ::: "memory");             \
    __builtin_amdgcn_s_barrier();                                  \
    __builtin_amdgcn_sched_barrier(0);                             \
  } while (0)

__global__ __launch_bounds__(256) void prep_kernel(
    const float* __restrict__ w1, const float* __restrict__ w2,
    const float* __restrict__ b2,
    const float* __restrict__ g1, const float* __restrict__ be1,
    const float* __restrict__ m1, const float* __restrict__ v1,
    const float* __restrict__ g2, const float* __restrict__ be2,
    const float* __restrict__ m2, const float* __restrict__ v2,
    float* __restrict__ ws) {
  int tid = blockIdx.x * 256 + threadIdx.x;
  int nthr = gridDim.x * 256;
  for (int i = tid; i < CM * C; i += nthr) {
    int o = i / C, c = i - o * C;
    ws[W1T_OFF + c * CM + o] = w1[i];
  }
  // A fragments (bf16) for mfma_f32_16x16x32_bf16:
  // lane l holds A[row = mt*16 + (l&15)][k = ks*32 + (l>>4)*8 + j], j=0..7
  {
    ushort* abf = (ushort*)(ws + ABF_OFF);
    for (int i = tid; i < G * 4 * 2 * 64 * 8; i += nthr) {
      int j = i & 7, lane = (i >> 3) & 63, ks = (i >> 9) & 1;
      int mt = (i >> 10) & 3, g = (i >> 12) & 15;
      int m = mt * 16 + (lane & 15);
      int o = ks * 32 + ((lane >> 4) << 3) + j;
      float v = (m < K2) ? w2[(g * K2 + m) * CM + o] : 0.f;
      abf[i] = (ushort)f2bf_rne(v);
    }
  }
  for (int i = tid; i < G * 64; i += nthr) {
    int g = i >> 6, k = i & 63;
    ws[B2P_OFF + i] = (k < K2) ? b2[g * K2 + k] : 0.f;
  }
  if (tid < CM) {
    float inv = g1[tid] * rsqrtf(v1[tid] + EPSV);
    ws[S1_OFF + tid] = inv;
    ws[B1_OFF + tid] = be1[tid] - m1[tid] * inv;
  }
  if (tid < C) {
    float inv = g2[tid] * rsqrtf(v2[tid] + EPSV);
    ws[S2_OFF + tid] = inv;
    ws[B2C_OFF + tid] = be2[tid] - m2[tid] * inv;
  }
  if (tid < 16) ws[ZERO_OFF + tid] = 0.f;
}

// t = relu(bn1(w1 @ x)) stored as bf16, layout [b][tile16][pix256][o64].
__global__ __launch_bounds__(256) void t_kernel(
    const float* __restrict__ x, float* __restrict__ ws) {
  __shared__ float part[4][32][64];
  int p = threadIdx.x & 63;
  int q = __builtin_amdgcn_readfirstlane(threadIdx.x >> 6);
  int y = blockIdx.x, b = blockIdx.y, oh = blockIdx.z;
  const float* __restrict__ w1T = ws + W1T_OFF + oh * 32;

  float acc[32];
#pragma unroll
  for (int o = 0; o < 32; ++o) acc[o] = 0.f;
  const float* __restrict__ xrow = x + (((size_t)b * C + q * 64) * H + y) * W;
#pragma unroll 2
  for (int cc = 0; cc < 64; ++cc) {
    float xv = xrow[(size_t)cc * H * W + p];
    const float* __restrict__ wr = w1T + (q * 64 + cc) * CM;
#pragma unroll
    for (int o = 0; o < 32; ++o) acc[o] = fmaf(wr[o], xv, acc[o]);
  }
#pragma unroll
  for (int o = 0; o < 32; ++o) part[q][o][p] = acc[o];
  __syncthreads();

  int tile = (y >> 4) * 4 + (p >> 4);
  int pix = (y & 15) * 16 + (p & 15);
  const float* __restrict__ s1 = ws + S1_OFF + oh * 32;
  const float* __restrict__ b1 = ws + B1_OFF + oh * 32;
  float fv[8];
#pragma unroll
  for (int i = 0; i < 8; ++i) {
    int o = q * 8 + i;
    float s = part[0][o][p] + part[1][o][p] + part[2][o][p] + part[3][o][p];
    fv[i] = fmaxf(fmaf(s, s1[o], b1[o]), 0.f);
  }
  uint4 pk;
  pk.x = f2bf_rne(fv[0]) | (f2bf_rne(fv[1]) << 16);
  pk.y = f2bf_rne(fv[2]) | (f2bf_rne(fv[3]) << 16);
  pk.z = f2bf_rne(fv[4]) | (f2bf_rne(fv[5]) << 16);
  pk.w = f2bf_rne(fv[6]) | (f2bf_rne(fv[7]) << 16);
  ushort* tbf = (ushort*)(ws + TBF_OFF);
  size_t idx = (((size_t)(b * 16 + tile) * 256 + pix) * 64) + oh * 32 + q * 8;
  *(uint4*)(tbf + idx) = pk;
}

// per (b, g, 16x16 tile): MFMA wgt-GEMM -> transposed LDS [25 j][256 pix];
// halo in 2x4-channel double buffer; 4 stencil phases with counted vmcnt.
__global__ __launch_bounds__(256, 3) void inv_kernel(
    const float* __restrict__ x, const float* __restrict__ ws,
    float* __restrict__ out) {
  __shared__ uint wgt_u[25][256];     // 25.6 KB [j=k/2][pix]
  __shared__ float xh[2][4][HSLOTP];  // 22.8 KB: 2 buf x 4 ch x 22x32(+8)

  int tid = threadIdx.x;
  int lane = tid & 63;
  int wv = __builtin_amdgcn_readfirstlane(tid >> 6);
  int c16 = lane & 15, q = lane >> 4;
  int py = tid >> 4, chl = (tid >> 2) & 3, pq = tid & 3;
  int px0 = pq << 2;
  int tile = blockIdx.x, g = blockIdx.y, b = blockIdx.z;
  int ty = (tile >> 2) * TS, tx = (tile & 3) * TS;

  const ushort* abf = (const ushort*)(ws + ABF_OFF);
  const ushort* tbf = (const ushort*)(ws + TBF_OFF);

  // per-thread bn2 constants for the 4 phases (issued first, retire early)
  float scv[4], bcv[4];
#pragma unroll
  for (int p = 0; p < 4; ++p) {
    scv[p] = ws[S2_OFF + g * GC + p * 4 + chl];
    bcv[p] = ws[B2C_OFF + g * GC + p * 4 + chl];
  }

  // fragment + bias loads
  bf16x8 afr[4][2], bfr[4][2];
  f32x4 bias[4];
#pragma unroll
  for (int mt = 0; mt < 4; ++mt) {
#pragma unroll
    for (int ks = 0; ks < 2; ++ks)
      afr[mt][ks] = *(const bf16x8*)(abf + ((g * 8 + mt * 2 + ks) * 64 + lane) * 8);
    bias[mt] = *(const f32x4*)(ws + B2P_OFF + g * 64 + mt * 16 + q * 4);
  }
#pragma unroll
  for (int nt = 0; nt < 4; ++nt) {
    int pix = wv * 64 + nt * 16 + c16;
#pragma unroll
    for (int ks = 0; ks < 2; ++ks)
      bfr[nt][ks] = *(const bf16x8*)(
          tbf + (((size_t)(b * 16 + tile) * 256 + pix) * 64 + ks * 32 + q * 8));
  }

  // halo geometry: physical chunk cp at row holds logical cols ((cp^s8)*4..+3)
  uint hmask = 0;
  int hofs[11];
#pragma unroll
  for (int t2 = 0; t2 < 11; ++t2) {
    int f = t2 * 64 + lane;
    int row = f >> 5, cp = (f >> 2) & 7, sub = f & 3;
    int s8 = (row + 3 * (row >> 3)) & 7;
    int col = ((cp ^ s8) << 2) + sub;
    int gy = ty + row - PADD, gx = tx + col - PADD;
    bool v = (col < HALO_R) && ((unsigned)gy < H) && ((unsigned)gx < W);
    hmask |= (uint)v << t2;
    hofs[t2] = gy * W + gx;
  }
  const float* zsrc = ws + ZERO_OFF;
  const float* xg = x + ((size_t)b * C + g * GC) * (H * W);

#define STAGE(CH, BUF) do {                                         \
    const float* xc_ = xg + (size_t)(CH) * (H * W);                 \
    float* dst_ = &xh[BUF][(CH) & 3][0];                            \
    _Pragma("unroll")                                               \
    for (int t2 = 0; t2 < 11; ++t2) {                               \
      const float* s_ = ((hmask >> t2) & 1u) ? (xc_ + hofs[t2]) : zsrc; \
      gload_lds4(s_, dst_ + t2 * 64);                               \
    }                                                               \
  } while (0)

  // stage first 8 channels (wave wv stages ch wv and ch 4+wv)
  STAGE(wv, 0);
  STAGE(4 + wv, 1);

  // ---- MFMA GEMM + transposed pack --------------------------------------
#pragma unroll
  for (int nt = 0; nt < 4; ++nt) {
    f32x4 a[4];
#pragma unroll
    for (int mt = 0; mt < 4; ++mt) a[mt] = bias[mt];
#pragma unroll
    for (int ks = 0; ks < 2; ++ks)
#pragma unroll
      for (int mt = 0; mt < 4; ++mt)
        a[mt] = __builtin_amdgcn_mfma_f32_16x16x32_bf16(afr[mt][ks], bfr[nt][ks],
                                                        a[mt], 0, 0, 0);
    int pix = wv * 64 + nt * 16 + c16;
#pragma unroll
    for (int mt = 0; mt < 4; ++mt) {
      uint lo = f2bf_rne(a[mt][0]) | (f2bf_rne(a[mt][1]) << 16);
      uint hi = f2bf_rne(a[mt][2]) | (f2bf_rne(a[mt][3]) << 16);
      int j0v = mt * 8 + q * 2;     // u32 row = k/2
      if (j0v < 25) wgt_u[j0v][pix] = lo;
      if (j0v + 1 < 25) wgt_u[j0v + 1][pix] = hi;
    }
  }

  // ---- stencil phase (1 ch, 4 px per thread) -----------------------------
  auto phase = [&](int bufI, int p) {
    f32x4 acc = {0.f, 0.f, 0.f, 0.f};
#pragma unroll
    for (int di = 0; di < KS; ++di) {
      const int j0 = (di * 7) >> 1;
      uint4 wq[4];
#pragma unroll
      for (int m = 0; m < 4; ++m)
        wq[m] = *(const uint4*)&wgt_u[j0 + m][py * 16 + px0];
      int row = py + di;
      int s8 = (row + 3 * (row >> 3)) & 7;
      const float* hb = &xh[bufI][chl][row * HROWF];
      f32x4 h0 = *(const f32x4*)&hb[((pq + 0) ^ s8) << 2];
      f32x4 h1 = *(const f32x4*)&hb[((pq + 1) ^ s8) << 2];
      f32x4 h2 = *(const f32x4*)&hb[((pq + 2) ^ s8) << 2];
      float rw[12] = {h0[0], h0[1], h0[2], h0[3], h1[0], h1[1],
                      h1[2], h1[3], h2[0], h2[1], h2[2], h2[3]};
#pragma unroll
      for (int dj = 0; dj < KS; ++dj) {
        const int k = di * 7 + dj, m = (k >> 1) - j0, hf = k & 1;
#pragma unroll
        for (int i = 0; i < 4; ++i) {
          uint u = (&wq[m].x)[i];
          float wf = __uint_as_float(hf ? (u & 0xffff0000u) : (u << 16));
          acc[i] = fmaf(rw[i + dj], wf, acc[i]);
        }
      }
    }
    int ch = p * 4 + chl;
    float4 o4;
    o4.x = fmaxf(fmaf(acc[0], scv[p], bcv[p]), 0.f);
    o4.y = fmaxf(fmaf(acc[1], scv[p], bcv[p]), 0.f);
    o4.z = fmaxf(fmaf(acc[2], scv[p], bcv[p]), 0.f);
    o4.w = fmaxf(fmaf(acc[3], scv[p], bcv[p]), 0.f);
    *(float4*)(out + (((size_t)b * C + g * GC + ch) * H + ty + py) * W + tx + px0) = o4;
  };

  // pipeline: buf0 ready (buf1's 11 still allowed outstanding)
  WAITBAR(11);
  phase(0, 0);                 // ch 0-3, +1 store
  BARRIER_ONLY();              // all waves done reading buf0
  STAGE(8 + wv, 0);            // refill buf0
  WAITBAR(12);                 // buf1 ready (leave st0 + ch8-11 = 12)
  phase(1, 1);                 // ch 4-7
  BARRIER_ONLY();              // all waves done reading buf1
  STAGE(12 + wv, 1);           // refill buf1
  WAITBAR(12);                 // buf0(ch8-11) ready (leave st1 + ch12-15)
  phase(0, 2);                 // ch 8-11
  WAITBAR(1);                  // buf1(ch12-15) ready (leave st2)
  phase(1, 3);                 // ch 12-15
#undef STAGE
}

extern "C" void kernel_launch(void* const* d_in, const int* in_sizes, int n_in,
                              void* d_out, int out_size, void* d_ws, size_t ws_size,
                              hipStream_t stream) {
  const float* x   = (const float*)d_in[0];
  const float* w1  = (const float*)d_in[1];
  const float* g1  = (const float*)d_in[2];
  const float* be1 = (const float*)d_in[3];
  const float* m1  = (const float*)d_in[4];
  const float* v1  = (const float*)d_in[5];
  const float* w2  = (const float*)d_in[6];
  const float* b2  = (const float*)d_in[7];
  const float* g2  = (const float*)d_in[8];
  const float* be2 = (const float*)d_in[9];
  const float* m2  = (const float*)d_in[10];
  const float* v2  = (const float*)d_in[11];
  float* outp = (float*)d_out;
  float* ws = (float*)d_ws;

  prep_kernel<<<dim3(64), dim3(256), 0, stream>>>(w1, w2, b2, g1, be1, m1, v1,
                                                  g2, be2, m2, v2, ws);
  t_kernel<<<dim3(H, BN, 2), dim3(256), 0, stream>>>(x, ws);
  inv_kernel<<<dim3(16, G, BN), dim3(256), 0, stream>>>(x, ws, outp);
}